// Round 8
// baseline (903.085 us; speedup 1.0000x reference)
//
#include <hip/hip_runtime.h>
#include <cstdint>

#define NB 2
#define NPER 65536
#define NPTS (NB*NPER)
#define CDIM 128
#define SV 64
#define VOX (SV*SV*SV)
#define WCOLS 1217
#define WSTRIDE 1232   // padded row stride in LDS (multiple of 16 floats)

typedef float f2 __attribute__((ext_vector_type(2)));

__device__ __forceinline__ f2 mk2(float a, float b){ f2 r; r.x=a; r.y=b; return r; }
__device__ __forceinline__ f2 pkfma(f2 a, f2 b, f2 c){
#if __has_builtin(__builtin_elementwise_fma)
    return __builtin_elementwise_fma(a, b, c);
#else
    f2 r; r.x = fmaf(a.x, b.x, c.x); r.y = fmaf(a.y, b.y, c.y); return r;
#endif
}

// c_plane [B][C=128][VOX] -> ct [B][VOX][C=128]
__global__ __launch_bounds__(256) void transpose_kernel(const float* __restrict__ in,
                                                        float* __restrict__ out){
    __shared__ float tile[128][33];
    const int blk = blockIdx.x;        // NB * (VOX/32) blocks
    const int b  = blk >> 13;          // VOX/32 = 8192
    const int v0 = (blk & 8191) << 5;  // *32
    const int tx = threadIdx.x & 31;
    const int ty = threadIdx.x >> 5;   // 0..7
    const float* ip = in + (size_t)b*128*VOX + v0;
    #pragma unroll
    for (int cc = 0; cc < 16; cc++){
        int c = cc*8 + ty;
        tile[c][tx] = ip[(size_t)c*VOX + tx];
    }
    __syncthreads();
    const int cx = threadIdx.x & 127;
    const int vy = threadIdx.x >> 7;   // 0..1
    float* op = out + ((size_t)b*VOX + v0)*128;
    #pragma unroll
    for (int vv = 0; vv < 16; vv++){
        int v = vv*2 + vy;
        op[(size_t)v*128 + cx] = tile[cx][v];
    }
}

// wave-per-point trilinear sample from channel-last ct; lane handles 2 channels
__global__ __launch_bounds__(256) void sample_kernel(const float* __restrict__ pcl_mem,
                                                     const float* __restrict__ ct,
                                                     float* __restrict__ feats){
    const int tid  = threadIdx.x;
    const int lane = tid & 63;
    const int p    = blockIdx.x*4 + (tid >> 6);
    const int b    = p >> 16;

    float v0 = pcl_mem[3*p+0], v1 = pcl_mem[3*p+1], v2 = pcl_mem[3*p+2];
    auto src = [](float v){
        float g = 2.0f*v/63.0f - 1.0f;
        g = fminf(fmaxf(g, -2.0f), 2.0f);
        float t = (g + 1.0f)*0.5f*63.0f;
        return fminf(fmaxf(t, 0.0f), 63.0f);
    };
    float ix = src(v0), iy = src(v1), iz = src(v2);
    float fx = floorf(ix), fy = floorf(iy), fz = floorf(iz);
    float wx = ix-fx, wy = iy-fy, wz = iz-fz;
    int x0 = min(max((int)fx,0),63); int x1 = min(x0+1,63);
    int y0 = min(max((int)fy,0),63); int y1 = min(y0+1,63);
    int z0 = min(max((int)fz,0),63); int z1 = min(z0+1,63);
    float wx0 = 1.f-wx, wy0 = 1.f-wy, wz0 = 1.f-wz;

    const float2* base = (const float2*)ct + (size_t)b*VOX*64 + lane;
    float ax = 0.f, ay = 0.f;
#define CORNER(zz,yy,xx,wgt) { \
        float2 cv = base[(size_t)(((zz)*64+(yy))*64+(xx))*64]; \
        float w_ = (wgt); \
        ax = fmaf(w_, cv.x, ax); ay = fmaf(w_, cv.y, ay); }
    CORNER(z0,y0,x0, wz0*wy0*wx0);
    CORNER(z0,y0,x1, wz0*wy0*wx );
    CORNER(z0,y1,x0, wz0*wy *wx0);
    CORNER(z0,y1,x1, wz0*wy *wx );
    CORNER(z1,y0,x0, wz *wy0*wx0);
    CORNER(z1,y0,x1, wz *wy0*wx );
    CORNER(z1,y1,x0, wz *wy *wx0);
    CORNER(z1,y1,x1, wz *wy *wx );
#undef CORNER
    ((float2*)(feats + (size_t)p*CDIM))[lane] = make_float2(ax, ay);
}

// fallback (ws too small): thread per (point, channel), original layout
__global__ __launch_bounds__(256) void sample_slow_kernel(const float* __restrict__ pcl_mem,
                                                          const float* __restrict__ cpl,
                                                          float* __restrict__ feats){
    int gid = blockIdx.x*256 + threadIdx.x;   // p*128 + c
    int p = gid >> 7; int c = gid & 127;
    int b = p >> 16;
    float v0 = pcl_mem[3*p+0], v1 = pcl_mem[3*p+1], v2 = pcl_mem[3*p+2];
    auto src = [](float v){
        float g = 2.0f*v/63.0f - 1.0f;
        g = fminf(fmaxf(g, -2.0f), 2.0f);
        float t = (g + 1.0f)*0.5f*63.0f;
        return fminf(fmaxf(t, 0.0f), 63.0f);
    };
    float ix = src(v0), iy = src(v1), iz = src(v2);
    float fx = floorf(ix), fy = floorf(iy), fz = floorf(iz);
    float wx = ix-fx, wy = iy-fy, wz = iz-fz;
    int x0 = min(max((int)fx,0),63); int x1 = min(x0+1,63);
    int y0 = min(max((int)fy,0),63); int y1 = min(y0+1,63);
    int z0 = min(max((int)fz,0),63); int z1 = min(z0+1,63);
    float wx0 = 1.f-wx, wy0 = 1.f-wy, wz0 = 1.f-wz;
    const float* base = cpl + ((size_t)(b*128 + c))*VOX;
    float acc = 0.f;
    acc = fmaf(wz0*wy0*wx0, base[(z0*64+y0)*64+x0], acc);
    acc = fmaf(wz0*wy0*wx , base[(z0*64+y0)*64+x1], acc);
    acc = fmaf(wz0*wy *wx0, base[(z0*64+y1)*64+x0], acc);
    acc = fmaf(wz0*wy *wx , base[(z0*64+y1)*64+x1], acc);
    acc = fmaf(wz *wy0*wx0, base[(z1*64+y0)*64+x0], acc);
    acc = fmaf(wz *wy0*wx , base[(z1*64+y0)*64+x1], acc);
    acc = fmaf(wz *wy *wx0, base[(z1*64+y1)*64+x0], acc);
    acc = fmaf(wz *wy *wx , base[(z1*64+y1)*64+x1], acc);
    feats[gid] = acc;
}

// ---------------------------------------------------------------------------
// Fused MLP + hypernetwork, Wh3 in LDS, TWO POINTS PER THREAD.
//   block = 256 threads (4 waves), grid = 256 -> 1 block/CU, 512 points/CU.
// Round-8 rationale: round 7 was DS-pipe-bound — every wave streams the full
// ~154 KB Wh3 from LDS (~9800 uniform ds_read_b128); 8 waves/CU -> 78K DS
// instr per 512 points through ONE DS pipe. Two points/thread halves DS
// instr/CU (39K) at unchanged total VALU (a single wave64 saturates its
// SIMD-32 VALU at 2cyc/instr, so 1 wave/SIMD costs only lgkm hiding, which
// deep unrolled pipelining of known-address ds_reads covers).
// __launch_bounds__(256,1): VGPR cap 512 (LDS already limits to 1 block/CU)
// -> no spill (round 7's 12.8 MB scratch came from the 128-VGPR cap).
// Main contraction uses j-chunks of 8 (w2c[8]/point, not w2v[32]): same
// weight reads, same per-element FMA chains -> per-point arithmetic is
// bit-identical to rounds 6/7.
// ---------------------------------------------------------------------------
__global__ __launch_bounds__(256, 1) void mlp_kernel(
        const float* __restrict__ pcl_mem,
        const float* __restrict__ Wh1, const float* __restrict__ bh1,
        const float* __restrict__ Wh2, const float* __restrict__ bh2,
        const float* __restrict__ Wh3, const float* __restrict__ bh3,
        const float* __restrict__ feats,
        float* __restrict__ outp)
{
    __shared__ __align__(16) float W3s[32*WSTRIDE];   // 154 KB
    const int tid = threadIdx.x;       // 0..255
    const int pA  = blockIdx.x*512 + tid;
    const int pB  = pA + 256;

    // cooperative stage: Wh3 [32][1217] -> W3s [32][1232] (padded rows)
    for (int t = tid; t < 32*WCOLS; t += 256){
        int k = t / WCOLS;
        int c = t - k*WCOLS;
        W3s[k*WSTRIDE + c] = Wh3[t];
    }
    __syncthreads();

    float xA0, xA1, xA2, xB0, xB1, xB2;
    {
        float v0 = pcl_mem[3*pA+0], v1 = pcl_mem[3*pA+1], v2 = pcl_mem[3*pA+2];
        xA0 = v0 - truncf(v0) - 0.5f; xA1 = v1 - truncf(v1) - 0.5f; xA2 = v2 - truncf(v2) - 0.5f;
        float u0 = pcl_mem[3*pB+0], u1 = pcl_mem[3*pB+1], u2 = pcl_mem[3*pB+2];
        xB0 = u0 - truncf(u0) - 0.5f; xB1 = u1 - truncf(u1) - 0.5f; xB2 = u2 - truncf(u2) - 0.5f;
    }

    const float4* f4A = (const float4*)(feats + (size_t)pA*CDIM);
    const float4* f4B = (const float4*)(feats + (size_t)pB*CDIM);
    const float4* W1q = (const float4*)Wh1;
    const float4* W2q = (const float4*)Wh2;
    const float4* b1q = (const float4*)bh1;
    const float4* b2q = (const float4*)bh2;
    const float4* b3q = (const float4*)bh3;

    // ---- h1 = leaky(feats @ Wh1 + bh1), both points share weight reads ----
    f2 h1A[16], h1B[16];
    #pragma unroll
    for (int jv=0;jv<8;jv++){
        float4 bv=b1q[jv];
        h1A[2*jv]=mk2(bv.x,bv.y); h1A[2*jv+1]=mk2(bv.z,bv.w);
        h1B[2*jv]=mk2(bv.x,bv.y); h1B[2*jv+1]=mk2(bv.z,bv.w);
    }
    for (int c4=0;c4<32;c4++){
        float4 fa = f4A[c4], fb = f4B[c4];
        float fsA[4] = {fa.x, fa.y, fa.z, fa.w};
        float fsB[4] = {fb.x, fb.y, fb.z, fb.w};
        #pragma unroll
        for (int cc=0;cc<4;cc++){
            f2 fcA = mk2(fsA[cc], fsA[cc]);
            f2 fcB = mk2(fsB[cc], fsB[cc]);
            #pragma unroll
            for (int jv=0;jv<8;jv++){
                float4 w = W1q[(c4*4+cc)*8 + jv];
                f2 wlo = mk2(w.x,w.y), whi = mk2(w.z,w.w);
                h1A[2*jv]   = pkfma(fcA, wlo, h1A[2*jv]);
                h1A[2*jv+1] = pkfma(fcA, whi, h1A[2*jv+1]);
                h1B[2*jv]   = pkfma(fcB, wlo, h1B[2*jv]);
                h1B[2*jv+1] = pkfma(fcB, whi, h1B[2*jv+1]);
            }
        }
    }
    float haA[32], haB[32];
    #pragma unroll
    for (int t=0;t<16;t++){
        float a0=h1A[t].x, a1=h1A[t].y, b0=h1B[t].x, b1=h1B[t].y;
        haA[2*t]=fmaxf(a0,0.01f*a0); haA[2*t+1]=fmaxf(a1,0.01f*a1);
        haB[2*t]=fmaxf(b0,0.01f*b0); haB[2*t+1]=fmaxf(b1,0.01f*b1);
    }

    // ---- h2 = leaky(h1a @ Wh2 + bh2), j fully unrolled ----
    f2 h2A[16], h2B[16];
    #pragma unroll
    for (int kv=0;kv<8;kv++){
        float4 bv=b2q[kv];
        h2A[2*kv]=mk2(bv.x,bv.y); h2A[2*kv+1]=mk2(bv.z,bv.w);
        h2B[2*kv]=mk2(bv.x,bv.y); h2B[2*kv+1]=mk2(bv.z,bv.w);
    }
    #pragma unroll
    for (int j=0;j<32;j++){
        f2 ajA = mk2(haA[j], haA[j]);
        f2 ajB = mk2(haB[j], haB[j]);
        #pragma unroll
        for (int kv=0;kv<8;kv++){
            float4 w = W2q[j*8+kv];
            f2 wlo = mk2(w.x,w.y), whi = mk2(w.z,w.w);
            h2A[2*kv]   = pkfma(ajA, wlo, h2A[2*kv]);
            h2A[2*kv+1] = pkfma(ajA, whi, h2A[2*kv+1]);
            h2B[2*kv]   = pkfma(ajB, wlo, h2B[2*kv]);
            h2B[2*kv+1] = pkfma(ajB, whi, h2B[2*kv+1]);
        }
    }
    float h2aA[32], h2aB[32];
    #pragma unroll
    for (int t=0;t<16;t++){
        float a0=h2A[t].x, a1=h2A[t].y, b0=h2B[t].x, b1=h2B[t].y;
        h2aA[2*t]=fmaxf(a0,0.01f*a0); h2aA[2*t+1]=fmaxf(a1,0.01f*a1);
        h2aB[2*t]=fmaxf(b0,0.01f*b0); h2aB[2*t+1]=fmaxf(b1,0.01f*b1);
    }

    const f2 xa0=mk2(xA0,xA0), xa1=mk2(xA1,xA1), xa2=mk2(xA2,xA2);
    const f2 xb0=mk2(xB0,xB0), xb1=mk2(xB1,xB1), xb2=mk2(xB2,xB2);

    // ---- o1[j] = x . W1'[:,j] + b1'[j] (hw cols 0..127), weights from LDS ----
    float a1A[32], a1B[32];
    #pragma unroll
    for (int jc=0;jc<4;jc++){
        f2 accA[4], accB[4];
        #pragma unroll
        for (int q=0;q<2;q++){
            float4 ba=b3q[jc*2+q], bb=b3q[8+jc*2+q], bc=b3q[16+jc*2+q], bd=b3q[24+jc*2+q];
            f2 balo=mk2(ba.x,ba.y), bahi=mk2(ba.z,ba.w);
            f2 bblo=mk2(bb.x,bb.y), bbhi=mk2(bb.z,bb.w);
            f2 bclo=mk2(bc.x,bc.y), bchi=mk2(bc.z,bc.w);
            f2 bdlo=mk2(bd.x,bd.y), bdhi=mk2(bd.z,bd.w);
            accA[2*q]   = pkfma(xa0,balo, pkfma(xa1,bblo, pkfma(xa2,bclo, bdlo)));
            accA[2*q+1] = pkfma(xa0,bahi, pkfma(xa1,bbhi, pkfma(xa2,bchi, bdhi)));
            accB[2*q]   = pkfma(xb0,balo, pkfma(xb1,bblo, pkfma(xb2,bclo, bdlo)));
            accB[2*q+1] = pkfma(xb0,bahi, pkfma(xb1,bbhi, pkfma(xb2,bchi, bdhi)));
        }
        #pragma unroll
        for (int k=0;k<32;k++){
            const float4* row = (const float4*)(W3s + k*WSTRIDE) + jc*2;
            f2 hkA = mk2(h2aA[k], h2aA[k]);
            f2 hkB = mk2(h2aB[k], h2aB[k]);
            #pragma unroll
            for (int q=0;q<2;q++){
                float4 wa=row[q], wb=row[8+q], wc=row[16+q], wd=row[24+q];
                f2 walo=mk2(wa.x,wa.y), wahi=mk2(wa.z,wa.w);
                f2 wblo=mk2(wb.x,wb.y), wbhi=mk2(wb.z,wb.w);
                f2 wclo=mk2(wc.x,wc.y), wchi=mk2(wc.z,wc.w);
                f2 wdlo=mk2(wd.x,wd.y), wdhi=mk2(wd.z,wd.w);
                f2 mA0 = pkfma(xa0,walo, pkfma(xa1,wblo, pkfma(xa2,wclo, wdlo)));
                f2 mA1 = pkfma(xa0,wahi, pkfma(xa1,wbhi, pkfma(xa2,wchi, wdhi)));
                f2 mB0 = pkfma(xb0,walo, pkfma(xb1,wblo, pkfma(xb2,wclo, wdlo)));
                f2 mB1 = pkfma(xb0,wahi, pkfma(xb1,wbhi, pkfma(xb2,wchi, wdhi)));
                accA[2*q]   = pkfma(hkA, mA0, accA[2*q]);
                accA[2*q+1] = pkfma(hkA, mA1, accA[2*q+1]);
                accB[2*q]   = pkfma(hkB, mB0, accB[2*q]);
                accB[2*q+1] = pkfma(hkB, mB1, accB[2*q+1]);
            }
        }
        #pragma unroll
        for (int q=0;q<2;q++){
            float a0=accA[2*q].x, a1=accA[2*q].y, a2=accA[2*q+1].x, a3=accA[2*q+1].y;
            a1A[jc*8+4*q+0]=fmaxf(a0,0.01f*a0); a1A[jc*8+4*q+1]=fmaxf(a1,0.01f*a1);
            a1A[jc*8+4*q+2]=fmaxf(a2,0.01f*a2); a1A[jc*8+4*q+3]=fmaxf(a3,0.01f*a3);
            float b0=accB[2*q].x, b1=accB[2*q].y, b2=accB[2*q+1].x, b3=accB[2*q+1].y;
            a1B[jc*8+4*q+0]=fmaxf(b0,0.01f*b0); a1B[jc*8+4*q+1]=fmaxf(b1,0.01f*b1);
            a1B[jc*8+4*q+2]=fmaxf(b2,0.01f*b2); a1B[jc*8+4*q+3]=fmaxf(b3,0.01f*b3);
        }
    }

    // ---- o2 init = b2' + h2a . W3[:,1152..1183], k unrolled ----
    f2 o2A[16], o2B[16];
    #pragma unroll
    for (int jv=0;jv<8;jv++){
        float4 bv=b3q[288+jv];
        o2A[2*jv]=mk2(bv.x,bv.y); o2A[2*jv+1]=mk2(bv.z,bv.w);
        o2B[2*jv]=mk2(bv.x,bv.y); o2B[2*jv+1]=mk2(bv.z,bv.w);
    }
    #pragma unroll
    for (int k=0;k<32;k++){
        const float4* row = (const float4*)(W3s + k*WSTRIDE) + 288;
        f2 hkA = mk2(h2aA[k], h2aA[k]);
        f2 hkB = mk2(h2aB[k], h2aB[k]);
        #pragma unroll
        for (int jv=0;jv<8;jv++){
            float4 w = row[jv];
            f2 wlo = mk2(w.x,w.y), whi = mk2(w.z,w.w);
            o2A[2*jv]   = pkfma(hkA, wlo, o2A[2*jv]);
            o2A[2*jv+1] = pkfma(hkA, whi, o2A[2*jv+1]);
            o2B[2*jv]   = pkfma(hkB, wlo, o2B[2*jv]);
            o2B[2*jv+1] = pkfma(hkB, whi, o2B[2*jv+1]);
        }
    }

    // ---- main contraction: o2[j] += sum_i a1[i]*(bh3 + h2.Wh3)[128+i*32+j].
    // j-chunks of 8 (w2c per point); a1 consumed head-first via static rotation.
    #pragma unroll 1
    for (int i=0;i<32;i++){
        f2 aiA = mk2(a1A[0], a1A[0]);
        f2 aiB = mk2(a1B[0], a1B[0]);
        #pragma unroll
        for (int jc=0;jc<4;jc++){
            f2 w2A[4], w2B[4];
            #pragma unroll
            for (int q=0;q<2;q++){
                float4 bv=b3q[32+i*8+jc*2+q];
                f2 blo=mk2(bv.x,bv.y), bhi=mk2(bv.z,bv.w);
                w2A[2*q]=blo; w2A[2*q+1]=bhi;
                w2B[2*q]=blo; w2B[2*q+1]=bhi;
            }
            #pragma unroll
            for (int k=0;k<32;k++){
                const float4* row = (const float4*)(W3s + k*WSTRIDE) + 32 + i*8 + jc*2;
                f2 hkA = mk2(h2aA[k], h2aA[k]);
                f2 hkB = mk2(h2aB[k], h2aB[k]);
                #pragma unroll
                for (int q=0;q<2;q++){
                    float4 w = row[q];
                    f2 wlo = mk2(w.x,w.y), whi = mk2(w.z,w.w);
                    w2A[2*q]   = pkfma(hkA, wlo, w2A[2*q]);
                    w2A[2*q+1] = pkfma(hkA, whi, w2A[2*q+1]);
                    w2B[2*q]   = pkfma(hkB, wlo, w2B[2*q]);
                    w2B[2*q+1] = pkfma(hkB, whi, w2B[2*q+1]);
                }
            }
            #pragma unroll
            for (int t=0;t<4;t++){
                o2A[jc*4+t] = pkfma(aiA, w2A[t], o2A[jc*4+t]);
                o2B[jc*4+t] = pkfma(aiB, w2B[t], o2B[jc*4+t]);
            }
        }
        #pragma unroll
        for (int t=0;t<31;t++){ a1A[t]=a1A[t+1]; a1B[t]=a1B[t+1]; }
    }

    // a2 = leaky(o2) in registers
    float a2A[32], a2B[32];
    #pragma unroll
    for (int t=0;t<16;t++){
        float a0=o2A[t].x, a1=o2A[t].y, b0=o2B[t].x, b1=o2B[t].y;
        a2A[2*t]=fmaxf(a0,0.01f*a0); a2A[2*t+1]=fmaxf(a1,0.01f*a1);
        a2B[2*t]=fmaxf(b0,0.01f*b0); a2B[2*t+1]=fmaxf(b1,0.01f*b1);
    }

    // ---- final: o3 = a2 . W3' + b3' (hw cols 1184..1216) ----
    float o3A = bh3[1216], o3B = bh3[1216];
    #pragma unroll
    for (int k=0;k<32;k++){
        float w = W3s[k*WSTRIDE + 1216];
        o3A = fmaf(h2aA[k], w, o3A);
        o3B = fmaf(h2aB[k], w, o3B);
    }
    #pragma unroll
    for (int jc=0;jc<4;jc++){
        float w3A[8], w3B[8];
        #pragma unroll
        for (int q=0;q<2;q++){
            float4 bv=b3q[296+jc*2+q];
            w3A[4*q]=bv.x; w3A[4*q+1]=bv.y; w3A[4*q+2]=bv.z; w3A[4*q+3]=bv.w;
            w3B[4*q]=bv.x; w3B[4*q+1]=bv.y; w3B[4*q+2]=bv.z; w3B[4*q+3]=bv.w;
        }
        #pragma unroll
        for (int k=0;k<32;k++){
            const float4* row = (const float4*)(W3s + k*WSTRIDE) + 296 + jc*2;
            float hkA = h2aA[k], hkB = h2aB[k];
            #pragma unroll
            for (int q=0;q<2;q++){
                float4 w=row[q];
                w3A[4*q+0]=fmaf(hkA,w.x,w3A[4*q+0]); w3A[4*q+1]=fmaf(hkA,w.y,w3A[4*q+1]);
                w3A[4*q+2]=fmaf(hkA,w.z,w3A[4*q+2]); w3A[4*q+3]=fmaf(hkA,w.w,w3A[4*q+3]);
                w3B[4*q+0]=fmaf(hkB,w.x,w3B[4*q+0]); w3B[4*q+1]=fmaf(hkB,w.y,w3B[4*q+1]);
                w3B[4*q+2]=fmaf(hkB,w.z,w3B[4*q+2]); w3B[4*q+3]=fmaf(hkB,w.w,w3B[4*q+3]);
            }
        }
        #pragma unroll
        for (int r=0;r<8;r++){
            o3A = fmaf(a2A[jc*8+r], w3A[r], o3A);
            o3B = fmaf(a2B[jc*8+r], w3B[r], o3B);
        }
    }

    outp[pA] = o3A;
    outp[pB] = o3B;
}

extern "C" void kernel_launch(void* const* d_in, const int* in_sizes, int n_in,
                              void* d_out, int out_size, void* d_ws, size_t ws_size,
                              hipStream_t stream)
{
    const float* pcl_mem = (const float*)d_in[1];
    const float* c_plane = (const float*)d_in[2];
    const float* Wh1     = (const float*)d_in[3];
    const float* bh1     = (const float*)d_in[4];
    const float* Wh2     = (const float*)d_in[5];
    const float* bh2     = (const float*)d_in[6];
    const float* Wh3     = (const float*)d_in[7];
    const float* bh3     = (const float*)d_in[8];
    float* outp  = (float*)d_out;
    float* feats = outp + NPTS;

    const size_t ct_bytes = (size_t)NB*VOX*CDIM*sizeof(float);   // 256 MiB
    if (ws_size >= ct_bytes) {
        float* ct = (float*)d_ws;
        transpose_kernel<<<NB*(VOX/32), 256, 0, stream>>>(c_plane, ct);
        sample_kernel<<<NPTS/4, 256, 0, stream>>>(pcl_mem, ct, feats);
    } else {
        sample_slow_kernel<<<(NPTS*CDIM)/256, 256, 0, stream>>>(pcl_mem, c_plane, feats);
    }

    mlp_kernel<<<NPTS/512, 256, 0, stream>>>(pcl_mem, Wh1, bh1, Wh2, bh2, Wh3, bh3, feats, outp);
}

// Round 9
// 711.574 us; speedup vs baseline: 1.2691x; 1.2691x over previous
//
#include <hip/hip_runtime.h>
#include <cstdint>

#define NB 2
#define NPER 65536
#define NPTS (NB*NPER)
#define CDIM 128
#define SV 64
#define VOX (SV*SV*SV)
#define WCOLS 1217
#define WSTRIDE 1232   // padded row stride in LDS (multiple of 16 floats)

typedef float f2 __attribute__((ext_vector_type(2)));

__device__ __forceinline__ f2 mk2(float a, float b){ f2 r; r.x=a; r.y=b; return r; }
__device__ __forceinline__ f2 pkfma(f2 a, f2 b, f2 c){
#if __has_builtin(__builtin_elementwise_fma)
    return __builtin_elementwise_fma(a, b, c);
#else
    f2 r; r.x = fmaf(a.x, b.x, c.x); r.y = fmaf(a.y, b.y, c.y); return r;
#endif
}

// c_plane [B][C=128][VOX] -> ct [B][VOX][C=128]
__global__ __launch_bounds__(256) void transpose_kernel(const float* __restrict__ in,
                                                        float* __restrict__ out){
    __shared__ float tile[128][33];
    const int blk = blockIdx.x;        // NB * (VOX/32) blocks
    const int b  = blk >> 13;          // VOX/32 = 8192
    const int v0 = (blk & 8191) << 5;  // *32
    const int tx = threadIdx.x & 31;
    const int ty = threadIdx.x >> 5;   // 0..7
    const float* ip = in + (size_t)b*128*VOX + v0;
    #pragma unroll
    for (int cc = 0; cc < 16; cc++){
        int c = cc*8 + ty;
        tile[c][tx] = ip[(size_t)c*VOX + tx];
    }
    __syncthreads();
    const int cx = threadIdx.x & 127;
    const int vy = threadIdx.x >> 7;   // 0..1
    float* op = out + ((size_t)b*VOX + v0)*128;
    #pragma unroll
    for (int vv = 0; vv < 16; vv++){
        int v = vv*2 + vy;
        op[(size_t)v*128 + cx] = tile[cx][v];
    }
}

// wave-per-point trilinear sample from channel-last ct; lane handles 2 channels
__global__ __launch_bounds__(256) void sample_kernel(const float* __restrict__ pcl_mem,
                                                     const float* __restrict__ ct,
                                                     float* __restrict__ feats){
    const int tid  = threadIdx.x;
    const int lane = tid & 63;
    const int p    = blockIdx.x*4 + (tid >> 6);
    const int b    = p >> 16;

    float v0 = pcl_mem[3*p+0], v1 = pcl_mem[3*p+1], v2 = pcl_mem[3*p+2];
    auto src = [](float v){
        float g = 2.0f*v/63.0f - 1.0f;
        g = fminf(fmaxf(g, -2.0f), 2.0f);
        float t = (g + 1.0f)*0.5f*63.0f;
        return fminf(fmaxf(t, 0.0f), 63.0f);
    };
    float ix = src(v0), iy = src(v1), iz = src(v2);
    float fx = floorf(ix), fy = floorf(iy), fz = floorf(iz);
    float wx = ix-fx, wy = iy-fy, wz = iz-fz;
    int x0 = min(max((int)fx,0),63); int x1 = min(x0+1,63);
    int y0 = min(max((int)fy,0),63); int y1 = min(y0+1,63);
    int z0 = min(max((int)fz,0),63); int z1 = min(z0+1,63);
    float wx0 = 1.f-wx, wy0 = 1.f-wy, wz0 = 1.f-wz;

    const float2* base = (const float2*)ct + (size_t)b*VOX*64 + lane;
    float ax = 0.f, ay = 0.f;
#define CORNER(zz,yy,xx,wgt) { \
        float2 cv = base[(size_t)(((zz)*64+(yy))*64+(xx))*64]; \
        float w_ = (wgt); \
        ax = fmaf(w_, cv.x, ax); ay = fmaf(w_, cv.y, ay); }
    CORNER(z0,y0,x0, wz0*wy0*wx0);
    CORNER(z0,y0,x1, wz0*wy0*wx );
    CORNER(z0,y1,x0, wz0*wy *wx0);
    CORNER(z0,y1,x1, wz0*wy *wx );
    CORNER(z1,y0,x0, wz *wy0*wx0);
    CORNER(z1,y0,x1, wz *wy0*wx );
    CORNER(z1,y1,x0, wz *wy *wx0);
    CORNER(z1,y1,x1, wz *wy *wx );
#undef CORNER
    ((float2*)(feats + (size_t)p*CDIM))[lane] = make_float2(ax, ay);
}

// fallback (ws too small): thread per (point, channel), original layout
__global__ __launch_bounds__(256) void sample_slow_kernel(const float* __restrict__ pcl_mem,
                                                          const float* __restrict__ cpl,
                                                          float* __restrict__ feats){
    int gid = blockIdx.x*256 + threadIdx.x;   // p*128 + c
    int p = gid >> 7; int c = gid & 127;
    int b = p >> 16;
    float v0 = pcl_mem[3*p+0], v1 = pcl_mem[3*p+1], v2 = pcl_mem[3*p+2];
    auto src = [](float v){
        float g = 2.0f*v/63.0f - 1.0f;
        g = fminf(fmaxf(g, -2.0f), 2.0f);
        float t = (g + 1.0f)*0.5f*63.0f;
        return fminf(fmaxf(t, 0.0f), 63.0f);
    };
    float ix = src(v0), iy = src(v1), iz = src(v2);
    float fx = floorf(ix), fy = floorf(iy), fz = floorf(iz);
    float wx = ix-fx, wy = iy-fy, wz = iz-fz;
    int x0 = min(max((int)fx,0),63); int x1 = min(x0+1,63);
    int y0 = min(max((int)fy,0),63); int y1 = min(y0+1,63);
    int z0 = min(max((int)fz,0),63); int z1 = min(z0+1,63);
    float wx0 = 1.f-wx, wy0 = 1.f-wy, wz0 = 1.f-wz;
    const float* base = cpl + ((size_t)(b*128 + c))*VOX;
    float acc = 0.f;
    acc = fmaf(wz0*wy0*wx0, base[(z0*64+y0)*64+x0], acc);
    acc = fmaf(wz0*wy0*wx , base[(z0*64+y0)*64+x1], acc);
    acc = fmaf(wz0*wy *wx0, base[(z0*64+y1)*64+x0], acc);
    acc = fmaf(wz0*wy *wx , base[(z0*64+y1)*64+x1], acc);
    acc = fmaf(wz *wy0*wx0, base[(z1*64+y0)*64+x0], acc);
    acc = fmaf(wz *wy0*wx , base[(z1*64+y0)*64+x1], acc);
    acc = fmaf(wz *wy *wx0, base[(z1*64+y1)*64+x0], acc);
    acc = fmaf(wz *wy *wx , base[(z1*64+y1)*64+x1], acc);
    feats[gid] = acc;
}

// ---------------------------------------------------------------------------
// Thread-per-point fused MLP + hypernetwork, Wh3 in LDS (154 KB, 512 thr/blk,
// grid = 256 -> 1 block/CU, 8 waves/CU = 2 waves/SIMD).
// Round-9 change vs round 7 (code otherwise byte-identical -> bit-identical
// output): __launch_bounds__(512, 2). LDS already caps us at 1 block/CU, so
// the per-wave VGPR budget at 2 waves/SIMD is 256 — the default 128 target
// was (a) spilling 12.8 MB of scratch and (b) limiting the scheduler's
// ds_read hoisting window (rounds 7/8 showed we're LDS-LATENCY-bound: perf
// scaled with wave count, not DS traffic). 256 VGPRs kill the spill and
// double the in-flight load window. Main i-loop unrolled 2x for a wider
// independent-work scheduling region (iterations independent except the 16
// trailing o2 accumulates).
// ---------------------------------------------------------------------------
__global__ __launch_bounds__(512, 2) void mlp_kernel(
        const float* __restrict__ pcl_mem,
        const float* __restrict__ Wh1, const float* __restrict__ bh1,
        const float* __restrict__ Wh2, const float* __restrict__ bh2,
        const float* __restrict__ Wh3, const float* __restrict__ bh3,
        const float* __restrict__ feats,
        float* __restrict__ outp)
{
    __shared__ __align__(16) float W3s[32*WSTRIDE];   // 154 KB
    const int tid = threadIdx.x;       // 0..511
    const int p   = blockIdx.x*512 + tid;

    // cooperative stage: Wh3 [32][1217] -> W3s [32][1232] (padded rows)
    for (int t = tid; t < 32*WCOLS; t += 512){
        int k = t / WCOLS;
        int c = t - k*WCOLS;
        W3s[k*WSTRIDE + c] = Wh3[t];
    }
    __syncthreads();

    float xv0, xv1, xv2;
    {
        float v0 = pcl_mem[3*p+0], v1 = pcl_mem[3*p+1], v2 = pcl_mem[3*p+2];
        xv0 = v0 - truncf(v0) - 0.5f;
        xv1 = v1 - truncf(v1) - 0.5f;
        xv2 = v2 - truncf(v2) - 0.5f;
    }

    const float4* f4  = (const float4*)(feats + (size_t)p*CDIM);
    const float4* W1q = (const float4*)Wh1;
    const float4* W2q = (const float4*)Wh2;
    const float4* b1q = (const float4*)bh1;
    const float4* b2q = (const float4*)bh2;
    const float4* b3q = (const float4*)bh3;

    // ---- h1 = leaky(feats @ Wh1 + bh1), packed pairs ----
    f2 h1v[16];
    #pragma unroll
    for (int jv=0;jv<8;jv++){ float4 bv=b1q[jv]; h1v[2*jv]=mk2(bv.x,bv.y); h1v[2*jv+1]=mk2(bv.z,bv.w); }
    for (int c4=0;c4<32;c4++){
        float4 f = f4[c4];
        float fs[4] = {f.x, f.y, f.z, f.w};
        #pragma unroll
        for (int cc=0;cc<4;cc++){
            f2 fc = mk2(fs[cc], fs[cc]);
            #pragma unroll
            for (int jv=0;jv<8;jv++){
                float4 w = W1q[(c4*4+cc)*8 + jv];
                h1v[2*jv]   = pkfma(fc, mk2(w.x,w.y), h1v[2*jv]);
                h1v[2*jv+1] = pkfma(fc, mk2(w.z,w.w), h1v[2*jv+1]);
            }
        }
    }
    float ha[32];
    #pragma unroll
    for (int t=0;t<16;t++){
        float a0=h1v[t].x, a1=h1v[t].y;
        ha[2*t]   = fmaxf(a0, 0.01f*a0);
        ha[2*t+1] = fmaxf(a1, 0.01f*a1);
    }

    // ---- h2 = leaky(h1a @ Wh2 + bh2), j fully unrolled ----
    f2 h2v[16];
    #pragma unroll
    for (int kv=0;kv<8;kv++){ float4 bv=b2q[kv]; h2v[2*kv]=mk2(bv.x,bv.y); h2v[2*kv+1]=mk2(bv.z,bv.w); }
    #pragma unroll
    for (int j=0;j<32;j++){
        f2 aj = mk2(ha[j], ha[j]);
        #pragma unroll
        for (int kv=0;kv<8;kv++){
            float4 w = W2q[j*8+kv];
            h2v[2*kv]   = pkfma(aj, mk2(w.x,w.y), h2v[2*kv]);
            h2v[2*kv+1] = pkfma(aj, mk2(w.z,w.w), h2v[2*kv+1]);
        }
    }
    float h2a[32];
    #pragma unroll
    for (int t=0;t<16;t++){
        float a0=h2v[t].x, a1=h2v[t].y;
        h2a[2*t]   = fmaxf(a0, 0.01f*a0);
        h2a[2*t+1] = fmaxf(a1, 0.01f*a1);
    }

    const f2 x0 = mk2(xv0,xv0), x1 = mk2(xv1,xv1), x2 = mk2(xv2,xv2);

    // ---- o1[j] = x . W1'[:,j] + b1'[j] (hw cols 0..127), weights from LDS.
    // jc fully unrolled -> a1r writes are static -> stays in registers.
    float a1r[32];
    #pragma unroll
    for (int jc=0;jc<4;jc++){
        f2 accv[4];
        #pragma unroll
        for (int q=0;q<2;q++){
            float4 ba=b3q[jc*2+q], bb=b3q[8+jc*2+q], bc=b3q[16+jc*2+q], bd=b3q[24+jc*2+q];
            accv[2*q]   = pkfma(x0,mk2(ba.x,ba.y), pkfma(x1,mk2(bb.x,bb.y), pkfma(x2,mk2(bc.x,bc.y), mk2(bd.x,bd.y))));
            accv[2*q+1] = pkfma(x0,mk2(ba.z,ba.w), pkfma(x1,mk2(bb.z,bb.w), pkfma(x2,mk2(bc.z,bc.w), mk2(bd.z,bd.w))));
        }
        #pragma unroll
        for (int k=0;k<32;k++){
            const float4* row = (const float4*)(W3s + k*WSTRIDE) + jc*2;
            f2 hk = mk2(h2a[k], h2a[k]);
            #pragma unroll
            for (int q=0;q<2;q++){
                float4 wa=row[q], wb=row[8+q], wc=row[16+q], wd=row[24+q];
                f2 m0 = pkfma(x0,mk2(wa.x,wa.y), pkfma(x1,mk2(wb.x,wb.y), pkfma(x2,mk2(wc.x,wc.y), mk2(wd.x,wd.y))));
                f2 m1 = pkfma(x0,mk2(wa.z,wa.w), pkfma(x1,mk2(wb.z,wb.w), pkfma(x2,mk2(wc.z,wc.w), mk2(wd.z,wd.w))));
                accv[2*q]   = pkfma(hk, m0, accv[2*q]);
                accv[2*q+1] = pkfma(hk, m1, accv[2*q+1]);
            }
        }
        #pragma unroll
        for (int q=0;q<2;q++){
            float a0=accv[2*q].x, a1=accv[2*q].y, a2=accv[2*q+1].x, a3=accv[2*q+1].y;
            a1r[jc*8+4*q+0] = fmaxf(a0, 0.01f*a0);
            a1r[jc*8+4*q+1] = fmaxf(a1, 0.01f*a1);
            a1r[jc*8+4*q+2] = fmaxf(a2, 0.01f*a2);
            a1r[jc*8+4*q+3] = fmaxf(a3, 0.01f*a3);
        }
    }

    // ---- o2 init = b2' + h2a . W3[:,1152..1183], k unrolled ----
    f2 o2v[16];
    #pragma unroll
    for (int jv=0;jv<8;jv++){ float4 bv=b3q[288+jv]; o2v[2*jv]=mk2(bv.x,bv.y); o2v[2*jv+1]=mk2(bv.z,bv.w); }
    #pragma unroll
    for (int k=0;k<32;k++){
        const float4* row = (const float4*)(W3s + k*WSTRIDE) + 288;
        f2 hk = mk2(h2a[k], h2a[k]);
        #pragma unroll
        for (int jv=0;jv<8;jv++){
            float4 w = row[jv];
            o2v[2*jv]   = pkfma(hk, mk2(w.x,w.y), o2v[2*jv]);
            o2v[2*jv+1] = pkfma(hk, mk2(w.z,w.w), o2v[2*jv+1]);
        }
    }

    // ---- main contraction: o2[j] += sum_i a1[i]*(bh3 + h2.Wh3)[128+i*32+j].
    // a1 consumed head-first with a STATIC rotation (keeps it in VGPRs).
    // unroll 2: wider independent scheduling window (needs the 256-VGPR cap).
    #pragma unroll 2
    for (int i=0;i<32;i++){
        f2 ai = mk2(a1r[0], a1r[0]);
        f2 w2v[16];
        #pragma unroll
        for (int jv=0;jv<8;jv++){ float4 bv=b3q[32+i*8+jv]; w2v[2*jv]=mk2(bv.x,bv.y); w2v[2*jv+1]=mk2(bv.z,bv.w); }
        #pragma unroll
        for (int k=0;k<32;k++){
            const float4* row = (const float4*)(W3s + k*WSTRIDE) + 32 + i*8;
            f2 hk = mk2(h2a[k], h2a[k]);
            #pragma unroll
            for (int jv=0;jv<8;jv++){
                float4 w = row[jv];
                w2v[2*jv]   = pkfma(hk, mk2(w.x,w.y), w2v[2*jv]);
                w2v[2*jv+1] = pkfma(hk, mk2(w.z,w.w), w2v[2*jv+1]);
            }
        }
        #pragma unroll
        for (int t=0;t<16;t++) o2v[t] = pkfma(ai, w2v[t], o2v[t]);
        #pragma unroll
        for (int t=0;t<31;t++) a1r[t] = a1r[t+1];
    }

    // a2 = leaky(o2) in registers
    float a2r[32];
    #pragma unroll
    for (int t=0;t<16;t++){
        float a0=o2v[t].x, a1=o2v[t].y;
        a2r[2*t]   = fmaxf(a0, 0.01f*a0);
        a2r[2*t+1] = fmaxf(a1, 0.01f*a1);
    }

    // ---- final: o3 = a2 . W3' + b3' (hw cols 1184..1216) ----
    float o3 = bh3[1216];
    #pragma unroll
    for (int k=0;k<32;k++) o3 = fmaf(h2a[k], W3s[k*WSTRIDE + 1216], o3);
    #pragma unroll
    for (int jc=0;jc<4;jc++){
        float w3c[8];
        #pragma unroll
        for (int q=0;q<2;q++){
            float4 bv=b3q[296+jc*2+q];
            w3c[4*q]=bv.x; w3c[4*q+1]=bv.y; w3c[4*q+2]=bv.z; w3c[4*q+3]=bv.w;
        }
        #pragma unroll
        for (int k=0;k<32;k++){
            const float4* row = (const float4*)(W3s + k*WSTRIDE) + 296 + jc*2;
            float hk = h2a[k];
            #pragma unroll
            for (int q=0;q<2;q++){
                float4 w=row[q];
                w3c[4*q+0] = fmaf(hk, w.x, w3c[4*q+0]);
                w3c[4*q+1] = fmaf(hk, w.y, w3c[4*q+1]);
                w3c[4*q+2] = fmaf(hk, w.z, w3c[4*q+2]);
                w3c[4*q+3] = fmaf(hk, w.w, w3c[4*q+3]);
            }
        }
        #pragma unroll
        for (int r=0;r<8;r++) o3 = fmaf(a2r[jc*8+r], w3c[r], o3);
    }

    outp[p] = o3;
}

extern "C" void kernel_launch(void* const* d_in, const int* in_sizes, int n_in,
                              void* d_out, int out_size, void* d_ws, size_t ws_size,
                              hipStream_t stream)
{
    const float* pcl_mem = (const float*)d_in[1];
    const float* c_plane = (const float*)d_in[2];
    const float* Wh1     = (const float*)d_in[3];
    const float* bh1     = (const float*)d_in[4];
    const float* Wh2     = (const float*)d_in[5];
    const float* bh2     = (const float*)d_in[6];
    const float* Wh3     = (const float*)d_in[7];
    const float* bh3     = (const float*)d_in[8];
    float* outp  = (float*)d_out;
    float* feats = outp + NPTS;

    const size_t ct_bytes = (size_t)NB*VOX*CDIM*sizeof(float);   // 256 MiB
    if (ws_size >= ct_bytes) {
        float* ct = (float*)d_ws;
        transpose_kernel<<<NB*(VOX/32), 256, 0, stream>>>(c_plane, ct);
        sample_kernel<<<NPTS/4, 256, 0, stream>>>(pcl_mem, ct, feats);
    } else {
        sample_slow_kernel<<<(NPTS*CDIM)/256, 256, 0, stream>>>(pcl_mem, c_plane, feats);
    }

    mlp_kernel<<<NPTS/512, 512, 0, stream>>>(pcl_mem, Wh1, bh1, Wh2, bh2, Wh3, bh3, feats, outp);
}

// Round 10
// 711.190 us; speedup vs baseline: 1.2698x; 1.0005x over previous
//
#include <hip/hip_runtime.h>
#include <cstdint>

#define NB 2
#define NPER 65536
#define NPTS (NB*NPER)
#define CDIM 128
#define SV 64
#define VOX (SV*SV*SV)
#define WCOLS 1217
#define WSTRIDE 1232   // padded row stride in LDS (multiple of 16 floats)

typedef float f2 __attribute__((ext_vector_type(2)));

__device__ __forceinline__ f2 mk2(float a, float b){ f2 r; r.x=a; r.y=b; return r; }
__device__ __forceinline__ f2 pkfma(f2 a, f2 b, f2 c){
#if __has_builtin(__builtin_elementwise_fma)
    return __builtin_elementwise_fma(a, b, c);
#else
    f2 r; r.x = fmaf(a.x, b.x, c.x); r.y = fmaf(a.y, b.y, c.y); return r;
#endif
}

// c_plane [B][C=128][VOX] -> ct [B][VOX][C=128]
__global__ __launch_bounds__(256) void transpose_kernel(const float* __restrict__ in,
                                                        float* __restrict__ out){
    __shared__ float tile[128][33];
    const int blk = blockIdx.x;        // NB * (VOX/32) blocks
    const int b  = blk >> 13;          // VOX/32 = 8192
    const int v0 = (blk & 8191) << 5;  // *32
    const int tx = threadIdx.x & 31;
    const int ty = threadIdx.x >> 5;   // 0..7
    const float* ip = in + (size_t)b*128*VOX + v0;
    #pragma unroll
    for (int cc = 0; cc < 16; cc++){
        int c = cc*8 + ty;
        tile[c][tx] = ip[(size_t)c*VOX + tx];
    }
    __syncthreads();
    const int cx = threadIdx.x & 127;
    const int vy = threadIdx.x >> 7;   // 0..1
    float* op = out + ((size_t)b*VOX + v0)*128;
    #pragma unroll
    for (int vv = 0; vv < 16; vv++){
        int v = vv*2 + vy;
        op[(size_t)v*128 + cx] = tile[cx][v];
    }
}

// wave-per-point trilinear sample from channel-last ct; lane handles 2 channels
__global__ __launch_bounds__(256) void sample_kernel(const float* __restrict__ pcl_mem,
                                                     const float* __restrict__ ct,
                                                     float* __restrict__ feats){
    const int tid  = threadIdx.x;
    const int lane = tid & 63;
    const int p    = blockIdx.x*4 + (tid >> 6);
    const int b    = p >> 16;

    float v0 = pcl_mem[3*p+0], v1 = pcl_mem[3*p+1], v2 = pcl_mem[3*p+2];
    auto src = [](float v){
        float g = 2.0f*v/63.0f - 1.0f;
        g = fminf(fmaxf(g, -2.0f), 2.0f);
        float t = (g + 1.0f)*0.5f*63.0f;
        return fminf(fmaxf(t, 0.0f), 63.0f);
    };
    float ix = src(v0), iy = src(v1), iz = src(v2);
    float fx = floorf(ix), fy = floorf(iy), fz = floorf(iz);
    float wx = ix-fx, wy = iy-fy, wz = iz-fz;
    int x0 = min(max((int)fx,0),63); int x1 = min(x0+1,63);
    int y0 = min(max((int)fy,0),63); int y1 = min(y0+1,63);
    int z0 = min(max((int)fz,0),63); int z1 = min(z0+1,63);
    float wx0 = 1.f-wx, wy0 = 1.f-wy, wz0 = 1.f-wz;

    const float2* base = (const float2*)ct + (size_t)b*VOX*64 + lane;
    float ax = 0.f, ay = 0.f;
#define CORNER(zz,yy,xx,wgt) { \
        float2 cv = base[(size_t)(((zz)*64+(yy))*64+(xx))*64]; \
        float w_ = (wgt); \
        ax = fmaf(w_, cv.x, ax); ay = fmaf(w_, cv.y, ay); }
    CORNER(z0,y0,x0, wz0*wy0*wx0);
    CORNER(z0,y0,x1, wz0*wy0*wx );
    CORNER(z0,y1,x0, wz0*wy *wx0);
    CORNER(z0,y1,x1, wz0*wy *wx );
    CORNER(z1,y0,x0, wz *wy0*wx0);
    CORNER(z1,y0,x1, wz *wy0*wx );
    CORNER(z1,y1,x0, wz *wy *wx0);
    CORNER(z1,y1,x1, wz *wy *wx );
#undef CORNER
    ((float2*)(feats + (size_t)p*CDIM))[lane] = make_float2(ax, ay);
}

// fallback (ws too small): thread per (point, channel), original layout
__global__ __launch_bounds__(256) void sample_slow_kernel(const float* __restrict__ pcl_mem,
                                                          const float* __restrict__ cpl,
                                                          float* __restrict__ feats){
    int gid = blockIdx.x*256 + threadIdx.x;   // p*128 + c
    int p = gid >> 7; int c = gid & 127;
    int b = p >> 16;
    float v0 = pcl_mem[3*p+0], v1 = pcl_mem[3*p+1], v2 = pcl_mem[3*p+2];
    auto src = [](float v){
        float g = 2.0f*v/63.0f - 1.0f;
        g = fminf(fmaxf(g, -2.0f), 2.0f);
        float t = (g + 1.0f)*0.5f*63.0f;
        return fminf(fmaxf(t, 0.0f), 63.0f);
    };
    float ix = src(v0), iy = src(v1), iz = src(v2);
    float fx = floorf(ix), fy = floorf(iy), fz = floorf(iz);
    float wx = ix-fx, wy = iy-fy, wz = iz-fz;
    int x0 = min(max((int)fx,0),63); int x1 = min(x0+1,63);
    int y0 = min(max((int)fy,0),63); int y1 = min(y0+1,63);
    int z0 = min(max((int)fz,0),63); int z1 = min(z0+1,63);
    float wx0 = 1.f-wx, wy0 = 1.f-wy, wz0 = 1.f-wz;
    const float* base = cpl + ((size_t)(b*128 + c))*VOX;
    float acc = 0.f;
    acc = fmaf(wz0*wy0*wx0, base[(z0*64+y0)*64+x0], acc);
    acc = fmaf(wz0*wy0*wx , base[(z0*64+y0)*64+x1], acc);
    acc = fmaf(wz0*wy *wx0, base[(z0*64+y1)*64+x0], acc);
    acc = fmaf(wz0*wy *wx , base[(z0*64+y1)*64+x1], acc);
    acc = fmaf(wz *wy0*wx0, base[(z1*64+y0)*64+x0], acc);
    acc = fmaf(wz *wy0*wx , base[(z1*64+y0)*64+x1], acc);
    acc = fmaf(wz *wy *wx0, base[(z1*64+y1)*64+x0], acc);
    acc = fmaf(wz *wy *wx , base[(z1*64+y1)*64+x1], acc);
    feats[gid] = acc;
}

// ---------------------------------------------------------------------------
// Thread-per-point fused MLP + hypernetwork, Wh3 in LDS (154 KB, 512 thr/blk,
// grid = 256 -> 1 block/CU, 8 waves/CU = 2 waves/SIMD).
// Round-10 change vs round 9 (code otherwise byte-identical -> bit-identical
// output): amdgpu_waves_per_eu(2,2). Round 9 proved launch_bounds' min-waves
// arg alone leaves the allocator targeting an occupancy it can never reach
// (LDS pins 1 block/CU): it throttled to 128 VGPRs and spilled 5 MB. Setting
// MAX waves/EU = 2 tells allocator+scheduler the budget is truly 256 VGPRs
// (per-SIMD file 512 wave-slots / 2 waves) -> no spill, deeper ds_read
// hoisting window. Evidence: round 8's (256,1) build allocated 156 VGPRs
// with zero spill; the 512-thread builds pinned at exactly 128 twice.
// ---------------------------------------------------------------------------
__global__ __launch_bounds__(512)
__attribute__((amdgpu_waves_per_eu(2, 2)))
void mlp_kernel(
        const float* __restrict__ pcl_mem,
        const float* __restrict__ Wh1, const float* __restrict__ bh1,
        const float* __restrict__ Wh2, const float* __restrict__ bh2,
        const float* __restrict__ Wh3, const float* __restrict__ bh3,
        const float* __restrict__ feats,
        float* __restrict__ outp)
{
    __shared__ __align__(16) float W3s[32*WSTRIDE];   // 154 KB
    const int tid = threadIdx.x;       // 0..511
    const int p   = blockIdx.x*512 + tid;

    // cooperative stage: Wh3 [32][1217] -> W3s [32][1232] (padded rows)
    for (int t = tid; t < 32*WCOLS; t += 512){
        int k = t / WCOLS;
        int c = t - k*WCOLS;
        W3s[k*WSTRIDE + c] = Wh3[t];
    }
    __syncthreads();

    float xv0, xv1, xv2;
    {
        float v0 = pcl_mem[3*p+0], v1 = pcl_mem[3*p+1], v2 = pcl_mem[3*p+2];
        xv0 = v0 - truncf(v0) - 0.5f;
        xv1 = v1 - truncf(v1) - 0.5f;
        xv2 = v2 - truncf(v2) - 0.5f;
    }

    const float4* f4  = (const float4*)(feats + (size_t)p*CDIM);
    const float4* W1q = (const float4*)Wh1;
    const float4* W2q = (const float4*)Wh2;
    const float4* b1q = (const float4*)bh1;
    const float4* b2q = (const float4*)bh2;
    const float4* b3q = (const float4*)bh3;

    // ---- h1 = leaky(feats @ Wh1 + bh1), packed pairs ----
    f2 h1v[16];
    #pragma unroll
    for (int jv=0;jv<8;jv++){ float4 bv=b1q[jv]; h1v[2*jv]=mk2(bv.x,bv.y); h1v[2*jv+1]=mk2(bv.z,bv.w); }
    for (int c4=0;c4<32;c4++){
        float4 f = f4[c4];
        float fs[4] = {f.x, f.y, f.z, f.w};
        #pragma unroll
        for (int cc=0;cc<4;cc++){
            f2 fc = mk2(fs[cc], fs[cc]);
            #pragma unroll
            for (int jv=0;jv<8;jv++){
                float4 w = W1q[(c4*4+cc)*8 + jv];
                h1v[2*jv]   = pkfma(fc, mk2(w.x,w.y), h1v[2*jv]);
                h1v[2*jv+1] = pkfma(fc, mk2(w.z,w.w), h1v[2*jv+1]);
            }
        }
    }
    float ha[32];
    #pragma unroll
    for (int t=0;t<16;t++){
        float a0=h1v[t].x, a1=h1v[t].y;
        ha[2*t]   = fmaxf(a0, 0.01f*a0);
        ha[2*t+1] = fmaxf(a1, 0.01f*a1);
    }

    // ---- h2 = leaky(h1a @ Wh2 + bh2), j fully unrolled ----
    f2 h2v[16];
    #pragma unroll
    for (int kv=0;kv<8;kv++){ float4 bv=b2q[kv]; h2v[2*kv]=mk2(bv.x,bv.y); h2v[2*kv+1]=mk2(bv.z,bv.w); }
    #pragma unroll
    for (int j=0;j<32;j++){
        f2 aj = mk2(ha[j], ha[j]);
        #pragma unroll
        for (int kv=0;kv<8;kv++){
            float4 w = W2q[j*8+kv];
            h2v[2*kv]   = pkfma(aj, mk2(w.x,w.y), h2v[2*kv]);
            h2v[2*kv+1] = pkfma(aj, mk2(w.z,w.w), h2v[2*kv+1]);
        }
    }
    float h2a[32];
    #pragma unroll
    for (int t=0;t<16;t++){
        float a0=h2v[t].x, a1=h2v[t].y;
        h2a[2*t]   = fmaxf(a0, 0.01f*a0);
        h2a[2*t+1] = fmaxf(a1, 0.01f*a1);
    }

    const f2 x0 = mk2(xv0,xv0), x1 = mk2(xv1,xv1), x2 = mk2(xv2,xv2);

    // ---- o1[j] = x . W1'[:,j] + b1'[j] (hw cols 0..127), weights from LDS.
    // jc fully unrolled -> a1r writes are static -> stays in registers.
    float a1r[32];
    #pragma unroll
    for (int jc=0;jc<4;jc++){
        f2 accv[4];
        #pragma unroll
        for (int q=0;q<2;q++){
            float4 ba=b3q[jc*2+q], bb=b3q[8+jc*2+q], bc=b3q[16+jc*2+q], bd=b3q[24+jc*2+q];
            accv[2*q]   = pkfma(x0,mk2(ba.x,ba.y), pkfma(x1,mk2(bb.x,bb.y), pkfma(x2,mk2(bc.x,bc.y), mk2(bd.x,bd.y))));
            accv[2*q+1] = pkfma(x0,mk2(ba.z,ba.w), pkfma(x1,mk2(bb.z,bb.w), pkfma(x2,mk2(bc.z,bc.w), mk2(bd.z,bd.w))));
        }
        #pragma unroll
        for (int k=0;k<32;k++){
            const float4* row = (const float4*)(W3s + k*WSTRIDE) + jc*2;
            f2 hk = mk2(h2a[k], h2a[k]);
            #pragma unroll
            for (int q=0;q<2;q++){
                float4 wa=row[q], wb=row[8+q], wc=row[16+q], wd=row[24+q];
                f2 m0 = pkfma(x0,mk2(wa.x,wa.y), pkfma(x1,mk2(wb.x,wb.y), pkfma(x2,mk2(wc.x,wc.y), mk2(wd.x,wd.y))));
                f2 m1 = pkfma(x0,mk2(wa.z,wa.w), pkfma(x1,mk2(wb.z,wb.w), pkfma(x2,mk2(wc.z,wc.w), mk2(wd.z,wd.w))));
                accv[2*q]   = pkfma(hk, m0, accv[2*q]);
                accv[2*q+1] = pkfma(hk, m1, accv[2*q+1]);
            }
        }
        #pragma unroll
        for (int q=0;q<2;q++){
            float a0=accv[2*q].x, a1=accv[2*q].y, a2=accv[2*q+1].x, a3=accv[2*q+1].y;
            a1r[jc*8+4*q+0] = fmaxf(a0, 0.01f*a0);
            a1r[jc*8+4*q+1] = fmaxf(a1, 0.01f*a1);
            a1r[jc*8+4*q+2] = fmaxf(a2, 0.01f*a2);
            a1r[jc*8+4*q+3] = fmaxf(a3, 0.01f*a3);
        }
    }

    // ---- o2 init = b2' + h2a . W3[:,1152..1183], k unrolled ----
    f2 o2v[16];
    #pragma unroll
    for (int jv=0;jv<8;jv++){ float4 bv=b3q[288+jv]; o2v[2*jv]=mk2(bv.x,bv.y); o2v[2*jv+1]=mk2(bv.z,bv.w); }
    #pragma unroll
    for (int k=0;k<32;k++){
        const float4* row = (const float4*)(W3s + k*WSTRIDE) + 288;
        f2 hk = mk2(h2a[k], h2a[k]);
        #pragma unroll
        for (int jv=0;jv<8;jv++){
            float4 w = row[jv];
            o2v[2*jv]   = pkfma(hk, mk2(w.x,w.y), o2v[2*jv]);
            o2v[2*jv+1] = pkfma(hk, mk2(w.z,w.w), o2v[2*jv+1]);
        }
    }

    // ---- main contraction: o2[j] += sum_i a1[i]*(bh3 + h2.Wh3)[128+i*32+j].
    // a1 consumed head-first with a STATIC rotation (keeps it in VGPRs).
    // unroll 2: wider independent scheduling window (uses the 256-VGPR cap).
    #pragma unroll 2
    for (int i=0;i<32;i++){
        f2 ai = mk2(a1r[0], a1r[0]);
        f2 w2v[16];
        #pragma unroll
        for (int jv=0;jv<8;jv++){ float4 bv=b3q[32+i*8+jv]; w2v[2*jv]=mk2(bv.x,bv.y); w2v[2*jv+1]=mk2(bv.z,bv.w); }
        #pragma unroll
        for (int k=0;k<32;k++){
            const float4* row = (const float4*)(W3s + k*WSTRIDE) + 32 + i*8;
            f2 hk = mk2(h2a[k], h2a[k]);
            #pragma unroll
            for (int jv=0;jv<8;jv++){
                float4 w = row[jv];
                w2v[2*jv]   = pkfma(hk, mk2(w.x,w.y), w2v[2*jv]);
                w2v[2*jv+1] = pkfma(hk, mk2(w.z,w.w), w2v[2*jv+1]);
            }
        }
        #pragma unroll
        for (int t=0;t<16;t++) o2v[t] = pkfma(ai, w2v[t], o2v[t]);
        #pragma unroll
        for (int t=0;t<31;t++) a1r[t] = a1r[t+1];
    }

    // a2 = leaky(o2) in registers
    float a2r[32];
    #pragma unroll
    for (int t=0;t<16;t++){
        float a0=o2v[t].x, a1=o2v[t].y;
        a2r[2*t]   = fmaxf(a0, 0.01f*a0);
        a2r[2*t+1] = fmaxf(a1, 0.01f*a1);
    }

    // ---- final: o3 = a2 . W3' + b3' (hw cols 1184..1216) ----
    float o3 = bh3[1216];
    #pragma unroll
    for (int k=0;k<32;k++) o3 = fmaf(h2a[k], W3s[k*WSTRIDE + 1216], o3);
    #pragma unroll
    for (int jc=0;jc<4;jc++){
        float w3c[8];
        #pragma unroll
        for (int q=0;q<2;q++){
            float4 bv=b3q[296+jc*2+q];
            w3c[4*q]=bv.x; w3c[4*q+1]=bv.y; w3c[4*q+2]=bv.z; w3c[4*q+3]=bv.w;
        }
        #pragma unroll
        for (int k=0;k<32;k++){
            const float4* row = (const float4*)(W3s + k*WSTRIDE) + 296 + jc*2;
            float hk = h2a[k];
            #pragma unroll
            for (int q=0;q<2;q++){
                float4 w=row[q];
                w3c[4*q+0] = fmaf(hk, w.x, w3c[4*q+0]);
                w3c[4*q+1] = fmaf(hk, w.y, w3c[4*q+1]);
                w3c[4*q+2] = fmaf(hk, w.z, w3c[4*q+2]);
                w3c[4*q+3] = fmaf(hk, w.w, w3c[4*q+3]);
            }
        }
        #pragma unroll
        for (int r=0;r<8;r++) o3 = fmaf(a2r[jc*8+r], w3c[r], o3);
    }

    outp[p] = o3;
}

extern "C" void kernel_launch(void* const* d_in, const int* in_sizes, int n_in,
                              void* d_out, int out_size, void* d_ws, size_t ws_size,
                              hipStream_t stream)
{
    const float* pcl_mem = (const float*)d_in[1];
    const float* c_plane = (const float*)d_in[2];
    const float* Wh1     = (const float*)d_in[3];
    const float* bh1     = (const float*)d_in[4];
    const float* Wh2     = (const float*)d_in[5];
    const float* bh2     = (const float*)d_in[6];
    const float* Wh3     = (const float*)d_in[7];
    const float* bh3     = (const float*)d_in[8];
    float* outp  = (float*)d_out;
    float* feats = outp + NPTS;

    const size_t ct_bytes = (size_t)NB*VOX*CDIM*sizeof(float);   // 256 MiB
    if (ws_size >= ct_bytes) {
        float* ct = (float*)d_ws;
        transpose_kernel<<<NB*(VOX/32), 256, 0, stream>>>(c_plane, ct);
        sample_kernel<<<NPTS/4, 256, 0, stream>>>(pcl_mem, ct, feats);
    } else {
        sample_slow_kernel<<<(NPTS*CDIM)/256, 256, 0, stream>>>(pcl_mem, c_plane, feats);
    }

    mlp_kernel<<<NPTS/512, 512, 0, stream>>>(pcl_mem, Wh1, bh1, Wh2, bh2, Wh3, bh3, feats, outp);
}